// Round 4
// baseline (40.078 us; speedup 1.0000x reference)
//
#include <hip/hip_runtime.h>
#include <math.h>

// Depthwise max-plus 5x5 correlation, pad=2, stride=1, dilation=1.
//   imgs: (8,32,256,256) f32, kernel: (32,1,5,5) f32, out same shape as imgs.
#define BB 8
#define CC 32
#define HH 256
#define WW 256

// Thread tile: 8 rows x 4 cols (32 outputs) — R2's proven shape.
// New vs R2: (1) wave-uniform scalars forced into SGPRs via readfirstlane
// (plane/row/weight addressing goes to the scalar unit), (2) explicit
// depth-1 row pipeline: load row s+1 before computing row s, so each
// global load has ~one full row of VALU work (~320 cyc) to hide under.
// Wave = 64 consecutive gids -> all lanes share p/rt; only x varies.
__global__ __launch_bounds__(256, 6) void selconv_kernel(
    const float* __restrict__ imgs,
    const float* __restrict__ kern,
    float* __restrict__ out)
{
    const int t    = threadIdx.x;
    const int lane = t & 63;
    // wave-uniform: force SGPR allocation
    const int wave = __builtin_amdgcn_readfirstlane(blockIdx.x * 4 + (t >> 6));
    const int p    = wave >> 5;           // plane b*C + c
    const int rt   = wave & 31;           // 8-row tile within plane
    const int c    = p & (CC - 1);
    const int y0   = rt * 8;
    const int x    = lane * 4;            // output col base (float4 aligned)

    // Uniform weight address -> s_load into SGPRs.
    float w[25];
    const float* kw = kern + c * 25;
#pragma unroll
    for (int i = 0; i < 25; ++i) w[i] = kw[i];

    const float NEG = -INFINITY;
    const float* plane = imgs + (size_t)p * (HH * WW);

    // Column-edge handling: clamp address (stay in-bounds), fix value by
    // cndmask to -inf. Only lanes 0 and 63 are affected.
    const bool okL = (x >= 4);
    const bool okR = (x + 4 < WW);
    const int  xm4 = okL ? x - 4 : 0;
    const int  xp4 = okR ? x + 4 : x;

    float acc[8][4];
#pragma unroll
    for (int r = 0; r < 8; ++r)
#pragma unroll
        for (int j = 0; j < 4; ++j) acc[r][j] = NEG;

    float bufA[12], bufB[12];

    // Load input row y0+iyo into buf (12 floats: cols x-4 .. x+7).
    auto loadrow = [&](float* buf, int iyo) {
        const int iy = y0 + iyo;
        if (iy < 0 || iy >= HH) return;          // wave-uniform branch
        const float* rp = plane + iy * WW;
        float4 qa = *reinterpret_cast<const float4*>(rp + xm4);
        float4 qb = *reinterpret_cast<const float4*>(rp + x);
        float4 qc = *reinterpret_cast<const float4*>(rp + xp4);
        buf[0] = okL ? qa.x : NEG;  buf[1] = okL ? qa.y : NEG;
        buf[2] = okL ? qa.z : NEG;  buf[3] = okL ? qa.w : NEG;
        buf[4] = qb.x;  buf[5] = qb.y;  buf[6] = qb.z;  buf[7] = qb.w;
        buf[8]  = okR ? qc.x : NEG; buf[9]  = okR ? qc.y : NEG;
        buf[10] = okR ? qc.z : NEG; buf[11] = okR ? qc.w : NEG;
    };

    // Apply input row iyo (in buf) to all output rows it feeds.
    auto computerow = [&](const float* buf, int iyo) {
        const int iy = y0 + iyo;
        if (iy < 0 || iy >= HH) return;          // wave-uniform branch
#pragma unroll
        for (int ky = 0; ky < 5; ++ky) {
            const int r = iyo + 2 - ky;          // compile-time after unroll
            if (r < 0 || r > 7) continue;
#pragma unroll
            for (int j = 0; j < 4; ++j) {
                const float s0 = buf[2 + j] + w[ky * 5 + 0];
                const float s1 = buf[3 + j] + w[ky * 5 + 1];
                const float s2 = buf[4 + j] + w[ky * 5 + 2];
                const float s3 = buf[5 + j] + w[ky * 5 + 3];
                const float s4 = buf[6 + j] + w[ky * 5 + 4];
                // 2x v_max3 + 1x v_max: max3(s0,s1,s2), max3(s3,s4,acc)
                acc[r][j] = fmaxf(fmaxf(fmaxf(s0, s1), s2),
                                  fmaxf(fmaxf(s3, s4), acc[r][j]));
            }
        }
    };

    // Depth-1 software pipeline over input rows y0-2 .. y0+9.
    loadrow(bufA, -2);
#pragma unroll
    for (int s = -2; s <= 9; ++s) {
        float* cur = ((s + 2) & 1) ? bufB : bufA;   // folds per iteration
        float* nxt = ((s + 3) & 1) ? bufB : bufA;
        if (s < 9) loadrow(nxt, s + 1);             // issue loads first
        computerow(cur, s);                         // then compute
    }

    float* op = out + (size_t)p * (HH * WW) + y0 * WW + x;
#pragma unroll
    for (int r = 0; r < 8; ++r) {
        *reinterpret_cast<float4*>(op + r * WW) =
            make_float4(acc[r][0], acc[r][1], acc[r][2], acc[r][3]);
    }
}

extern "C" void kernel_launch(void* const* d_in, const int* in_sizes, int n_in,
                              void* d_out, int out_size, void* d_ws, size_t ws_size,
                              hipStream_t stream)
{
    const float* imgs = (const float*)d_in[0];
    const float* kern = (const float*)d_in[1];
    float* out = (float*)d_out;

    // 8 planes*32ch * 32 row-tiles * 64 col-quads / 256 thr = 2048 blocks
    const int blocks = (BB * CC * (HH / 8) * (WW / 4)) / 256;
    selconv_kernel<<<blocks, 256, 0, stream>>>(imgs, kern, out);
}

// Round 5
// 30.925 us; speedup vs baseline: 1.2960x; 1.2960x over previous
//
#include <hip/hip_runtime.h>
#include <math.h>

// Depthwise max-plus 5x5 correlation, pad=2, stride=1, dilation=1.
//   imgs: (8,32,256,256) f32, kernel: (32,1,5,5) f32, out same shape.
#define BB 8
#define CC 32
#define HH 256
#define WW 256

// Thread tile: 8 rows x 4 cols (R2's proven shape, 31.5us baseline).
// Changes vs R2:
//  - exact-window loads: float2@(x-2) + float4@(x) + float2@(x+4) = 32B/row
//    (vs 48B), all naturally aligned; only 4 edge cndmasks per row.
//  - interior row-tiles (rt=1..30) take a branch-free path: one basic block
//    over all 12 input rows -> compiler hoists/pipelines loads itself.
//  - no lambda-held buffers with dynamic selection (R4 spill lesson); all
//    indices compile-time after unroll.
__global__ __launch_bounds__(256, 4) void selconv_kernel(
    const float* __restrict__ imgs,
    const float* __restrict__ kern,
    float* __restrict__ out)
{
    const int t    = threadIdx.x;
    const int lane = t & 63;
    // wave-uniform -> SGPR addressing
    const int wave = __builtin_amdgcn_readfirstlane((int)blockIdx.x * 4 + (t >> 6));
    const int p    = wave >> 5;          // plane b*C + c
    const int rt   = wave & 31;          // 8-row tile
    const int c    = p & (CC - 1);
    const int y0   = rt * 8;
    const int x    = lane * 4;           // output col base

    // Uniform weight address -> s_loads.
    float w[25];
    const float* kw = kern + c * 25;
#pragma unroll
    for (int i = 0; i < 25; ++i) w[i] = kw[i];

    const float NEG = -INFINITY;
    const float* plane = imgs + (size_t)p * (HH * WW);

    // Column-edge: clamp addresses in-bounds, fix values with cndmask.
    const bool okL = (lane != 0);
    const bool okR = (lane != 63);
    const int  xl  = okL ? x - 2 : 0;        // 8B-aligned
    const int  xr  = okR ? x + 4 : WW - 4;   // 16B-aligned

    float acc[8][4];
#pragma unroll
    for (int r = 0; r < 8; ++r)
#pragma unroll
        for (int j = 0; j < 4; ++j) acc[r][j] = NEG;

    // Apply one input row (index iyo relative to y0; compile-time after
    // unroll) to every output row it feeds.
    auto dorow = [&](int iyo) {
        const float* rp = plane + (y0 + iyo) * WW;
        const float2 L = *reinterpret_cast<const float2*>(rp + xl);
        const float4 M = *reinterpret_cast<const float4*>(rp + x);
        const float2 R = *reinterpret_cast<const float2*>(rp + xr);
        float v[8];
        v[0] = okL ? L.x : NEG;  v[1] = okL ? L.y : NEG;
        v[2] = M.x;  v[3] = M.y;  v[4] = M.z;  v[5] = M.w;
        v[6] = okR ? R.x : NEG;  v[7] = okR ? R.y : NEG;
#pragma unroll
        for (int ky = 0; ky < 5; ++ky) {
            const int r = iyo + 2 - ky;          // compile-time
            if (r < 0 || r > 7) continue;        // DCE'd
#pragma unroll
            for (int j = 0; j < 4; ++j) {
                const float s0 = v[j + 0] + w[ky * 5 + 0];
                const float s1 = v[j + 1] + w[ky * 5 + 1];
                const float s2 = v[j + 2] + w[ky * 5 + 2];
                const float s3 = v[j + 3] + w[ky * 5 + 3];
                const float s4 = v[j + 4] + w[ky * 5 + 4];
                // v_max3(s0,s1,s2), v_max3(s3,s4,acc), v_max
                acc[r][j] = fmaxf(fmaxf(fmaxf(s0, s1), s2),
                                  fmaxf(fmaxf(s3, s4), acc[r][j]));
            }
        }
    };

    if (rt != 0 && rt != 31) {
        // Interior: all 12 input rows valid -> branch-free straight line.
#pragma unroll
        for (int iyo = -2; iyo <= 9; ++iyo) dorow(iyo);
    } else {
        // Top/bottom tiles: per-row bounds check (wave-uniform).
#pragma unroll
        for (int iyo = -2; iyo <= 9; ++iyo) {
            const int iy = y0 + iyo;
            if (iy < 0 || iy >= HH) continue;
            dorow(iyo);
        }
    }

    float* op = out + (size_t)p * (HH * WW) + y0 * WW + x;
#pragma unroll
    for (int r = 0; r < 8; ++r) {
        *reinterpret_cast<float4*>(op + r * WW) =
            make_float4(acc[r][0], acc[r][1], acc[r][2], acc[r][3]);
    }
}

extern "C" void kernel_launch(void* const* d_in, const int* in_sizes, int n_in,
                              void* d_out, int out_size, void* d_ws, size_t ws_size,
                              hipStream_t stream)
{
    const float* imgs = (const float*)d_in[0];
    const float* kern = (const float*)d_in[1];
    float* out = (float*)d_out;

    // 256 planes * 32 row-tiles * 64 col-quads / 256 threads = 2048 blocks
    const int blocks = (BB * CC * (HH / 8) * (WW / 4)) / 256;
    selconv_kernel<<<blocks, 256, 0, stream>>>(imgs, kern, out);
}

// Round 6
// 30.734 us; speedup vs baseline: 1.3041x; 1.0062x over previous
//
#include <hip/hip_runtime.h>
#include <math.h>

// Depthwise max-plus 5x5 correlation, pad=2, stride=1, dilation=1.
//   imgs: (8,32,256,256) f32, kernel: (32,1,5,5) f32, out same shape.
#define BB 8
#define CC 32
#define HH 256
#define WW 256

// Thread tile: 8 rows x 4 cols (R2's proven shape, 31.5us baseline).
// Changes vs R2:
//  - exact-window loads: float2@(x-2) + float4@(x) + float2@(x+4) = 32B/row
//    (vs 48B), all naturally aligned; only 4 edge cndmasks per row.
//  - interior row-tiles (rt=1..30) take a branch-free path: one basic block
//    over all 12 input rows -> compiler hoists/pipelines loads itself.
//  - no lambda-held buffers with dynamic selection (R4 spill lesson); all
//    indices compile-time after unroll.
__global__ __launch_bounds__(256, 4) void selconv_kernel(
    const float* __restrict__ imgs,
    const float* __restrict__ kern,
    float* __restrict__ out)
{
    const int t    = threadIdx.x;
    const int lane = t & 63;
    // wave-uniform -> SGPR addressing
    const int wave = __builtin_amdgcn_readfirstlane((int)blockIdx.x * 4 + (t >> 6));
    const int p    = wave >> 5;          // plane b*C + c
    const int rt   = wave & 31;          // 8-row tile
    const int c    = p & (CC - 1);
    const int y0   = rt * 8;
    const int x    = lane * 4;           // output col base

    // Uniform weight address -> s_loads.
    float w[25];
    const float* kw = kern + c * 25;
#pragma unroll
    for (int i = 0; i < 25; ++i) w[i] = kw[i];

    const float NEG = -INFINITY;
    const float* plane = imgs + (size_t)p * (HH * WW);

    // Column-edge: clamp addresses in-bounds, fix values with cndmask.
    const bool okL = (lane != 0);
    const bool okR = (lane != 63);
    const int  xl  = okL ? x - 2 : 0;        // 8B-aligned
    const int  xr  = okR ? x + 4 : WW - 4;   // 16B-aligned

    float acc[8][4];
#pragma unroll
    for (int r = 0; r < 8; ++r)
#pragma unroll
        for (int j = 0; j < 4; ++j) acc[r][j] = NEG;

    // Apply one input row (index iyo relative to y0; compile-time after
    // unroll) to every output row it feeds.
    auto dorow = [&](int iyo) {
        const float* rp = plane + (y0 + iyo) * WW;
        const float2 L = *reinterpret_cast<const float2*>(rp + xl);
        const float4 M = *reinterpret_cast<const float4*>(rp + x);
        const float2 R = *reinterpret_cast<const float2*>(rp + xr);
        float v[8];
        v[0] = okL ? L.x : NEG;  v[1] = okL ? L.y : NEG;
        v[2] = M.x;  v[3] = M.y;  v[4] = M.z;  v[5] = M.w;
        v[6] = okR ? R.x : NEG;  v[7] = okR ? R.y : NEG;
#pragma unroll
        for (int ky = 0; ky < 5; ++ky) {
            const int r = iyo + 2 - ky;          // compile-time
            if (r < 0 || r > 7) continue;        // DCE'd
#pragma unroll
            for (int j = 0; j < 4; ++j) {
                const float s0 = v[j + 0] + w[ky * 5 + 0];
                const float s1 = v[j + 1] + w[ky * 5 + 1];
                const float s2 = v[j + 2] + w[ky * 5 + 2];
                const float s3 = v[j + 3] + w[ky * 5 + 3];
                const float s4 = v[j + 4] + w[ky * 5 + 4];
                // v_max3(s0,s1,s2), v_max3(s3,s4,acc), v_max
                acc[r][j] = fmaxf(fmaxf(fmaxf(s0, s1), s2),
                                  fmaxf(fmaxf(s3, s4), acc[r][j]));
            }
        }
    };

    if (rt != 0 && rt != 31) {
        // Interior: all 12 input rows valid -> branch-free straight line.
#pragma unroll
        for (int iyo = -2; iyo <= 9; ++iyo) dorow(iyo);
    } else {
        // Top/bottom tiles: per-row bounds check (wave-uniform).
#pragma unroll
        for (int iyo = -2; iyo <= 9; ++iyo) {
            const int iy = y0 + iyo;
            if (iy < 0 || iy >= HH) continue;
            dorow(iyo);
        }
    }

    float* op = out + (size_t)p * (HH * WW) + y0 * WW + x;
#pragma unroll
    for (int r = 0; r < 8; ++r) {
        *reinterpret_cast<float4*>(op + r * WW) =
            make_float4(acc[r][0], acc[r][1], acc[r][2], acc[r][3]);
    }
}

extern "C" void kernel_launch(void* const* d_in, const int* in_sizes, int n_in,
                              void* d_out, int out_size, void* d_ws, size_t ws_size,
                              hipStream_t stream)
{
    const float* imgs = (const float*)d_in[0];
    const float* kern = (const float*)d_in[1];
    float* out = (float*)d_out;

    // 256 planes * 32 row-tiles * 64 col-quads / 256 threads = 2048 blocks
    const int blocks = (BB * CC * (HH / 8) * (WW / 4)) / 256;
    selconv_kernel<<<blocks, 256, 0, stream>>>(imgs, kern, out);
}

// Round 7
// 30.350 us; speedup vs baseline: 1.3205x; 1.0126x over previous
//
#include <hip/hip_runtime.h>
#include <math.h>

// Depthwise max-plus 5x5 correlation, pad=2, stride=1, dilation=1.
//   imgs: (8,32,256,256) f32, kernel: (32,1,5,5) f32, out same shape.
#define BB 8
#define CC 32
#define HH 256
#define WW 256
#define TR 16            // output rows per block
#define LR (TR + 4)      // staged LDS rows (2+2 vertical halo)

typedef unsigned int u32;

// Block: 16 rows x 256 cols of one plane. Stage 20 input rows (20KB) into
// LDS with global_load_lds (1 instr = 1 full row per wave, coalesced 1KB),
// OOB halo rows filled with -inf so compute is branch-free for all blocks.
// Thread tile: 4 rows x 4 cols from LDS (3x ds_read_b128 per input row,
// stride-16B across lanes = conflict-free). acc16 + small staging keeps
// VGPR <= 64 -> 8 waves/SIMD (100% occupancy), which is the latency fix.
__global__ __launch_bounds__(256, 8) void selconv_kernel(
    const float* __restrict__ imgs,
    const float* __restrict__ kern,
    float* __restrict__ out)
{
    __shared__ float lds[LR * WW];          // 20 KB

    const int t    = threadIdx.x;
    const int lane = t & 63;
    const int wv   = t >> 6;                // wave 0..3 (uniform)
    const int p    = blockIdx.x >> 4;       // plane b*C + c (uniform)
    const int rt   = blockIdx.x & 15;       // row tile (uniform)
    const int c    = p & (CC - 1);
    const int y0   = rt * TR;
    const int x    = lane * 4;

    const float NEG = -INFINITY;
    const float* plane = imgs + (size_t)p * (HH * WW);

    // ---- Stage 20 rows: wave wv stages LDS rows 5*wv .. 5*wv+4 ----
    if (rt != 0 && rt != 15) {
#pragma unroll
        for (int i = 0; i < 5; ++i) {
            const int L  = wv * 5 + i;          // uniform
            const int iy = y0 - 2 + L;          // in-bounds for interior tiles
            __builtin_amdgcn_global_load_lds(
                (const __attribute__((address_space(1))) u32*)(plane + iy * WW + lane * 4),
                (__attribute__((address_space(3))) u32*)(&lds[L * WW]),
                16, 0, 0);
        }
    } else {
#pragma unroll
        for (int i = 0; i < 5; ++i) {
            const int L  = wv * 5 + i;
            const int iy = y0 - 2 + L;
            if (iy >= 0 && iy < HH) {           // wave-uniform
                __builtin_amdgcn_global_load_lds(
                    (const __attribute__((address_space(1))) u32*)(plane + iy * WW + lane * 4),
                    (__attribute__((address_space(3))) u32*)(&lds[L * WW]),
                    16, 0, 0);
            } else {
                *reinterpret_cast<float4*>(&lds[L * WW + lane * 4]) =
                    make_float4(NEG, NEG, NEG, NEG);
            }
        }
    }

    // Uniform weight address -> s_loads (overlaps with staging).
    float w[25];
    const float* kw = kern + c * 25;
#pragma unroll
    for (int i = 0; i < 25; ++i) w[i] = kw[i];

    __syncthreads();   // drains vmcnt (global_load_lds) + lgkmcnt

    // ---- Compute: wave wv owns output rows (rel) 4*wv .. 4*wv+3 ----
    const int or0 = wv * 4;
    const bool okL = (lane != 0);
    const bool okR = (lane != 63);
    const int  xl  = okL ? x - 4 : 0;       // clamped, fixed by cndmask
    const int  xr  = okR ? x + 4 : 0;

    float acc[4][4];
#pragma unroll
    for (int r = 0; r < 4; ++r)
#pragma unroll
        for (int j = 0; j < 4; ++j) acc[r][j] = NEG;

    // LDS rows needed: or0 .. or0+7 (output row or0+r, tap ky -> row or0+r+ky)
#pragma unroll
    for (int dl = 0; dl < 8; ++dl) {
        const float* lrow = &lds[(or0 + dl) * WW];
        const float4 A = *reinterpret_cast<const float4*>(lrow + xl);
        const float4 M = *reinterpret_cast<const float4*>(lrow + x);
        const float4 R = *reinterpret_cast<const float4*>(lrow + xr);
        // v[k] = input col (x-4+k); output col x+j needs v[j+2 .. j+6]
        float v[10];
        v[2] = okL ? A.z : NEG;  v[3] = okL ? A.w : NEG;
        v[4] = M.x;  v[5] = M.y;  v[6] = M.z;  v[7] = M.w;
        v[8] = okR ? R.x : NEG;  v[9] = okR ? R.y : NEG;
#pragma unroll
        for (int ky = 0; ky < 5; ++ky) {
            const int r = dl - ky;               // compile-time after unroll
            if (r < 0 || r > 3) continue;        // DCE'd
#pragma unroll
            for (int j = 0; j < 4; ++j) {
                const float s0 = v[j + 2] + w[ky * 5 + 0];
                const float s1 = v[j + 3] + w[ky * 5 + 1];
                const float s2 = v[j + 4] + w[ky * 5 + 2];
                const float s3 = v[j + 5] + w[ky * 5 + 3];
                const float s4 = v[j + 6] + w[ky * 5 + 4];
                // v_max3(s0,s1,s2), v_max3(s3,s4,acc), v_max
                acc[r][j] = fmaxf(fmaxf(fmaxf(s0, s1), s2),
                                  fmaxf(fmaxf(s3, s4), acc[r][j]));
            }
        }
    }

    float* op = out + (size_t)p * (HH * WW) + (y0 + or0) * WW + x;
#pragma unroll
    for (int r = 0; r < 4; ++r) {
        *reinterpret_cast<float4*>(op + r * WW) =
            make_float4(acc[r][0], acc[r][1], acc[r][2], acc[r][3]);
    }
}

extern "C" void kernel_launch(void* const* d_in, const int* in_sizes, int n_in,
                              void* d_out, int out_size, void* d_ws, size_t ws_size,
                              hipStream_t stream)
{
    const float* imgs = (const float*)d_in[0];
    const float* kern = (const float*)d_in[1];
    float* out = (float*)d_out;

    // 256 planes * 16 row-tiles = 4096 blocks x 256 threads
    const int blocks = BB * CC * (HH / TR);
    selconv_kernel<<<blocks, 256, 0, stream>>>(imgs, kern, out);
}